// Round 5
// baseline (723.899 us; speedup 1.0000x reference)
//
#include <hip/hip_runtime.h>
#include <hip/hip_fp16.h>

#define FDIM 128
#define SCAN_B 1024   // elements per scan block

// ---------------- init: self-loop degree ------------------------------------
__global__ void k_init(int* __restrict__ cnt, int n) {
    int i = blockIdx.x * 256 + threadIdx.x;
    if (i < n) cnt[i] = 1;
}

// ---------------- degree count: 8 edges/thread, fire-and-forget atomics -----
__global__ void k_count(const int* __restrict__ row, int* __restrict__ cnt, int nE) {
    int t = blockIdx.x * 256 + threadIdx.x;
    int base = t * 8;
    if (base >= nE) return;
    if (base + 8 <= nE) {
        const int4* r4 = reinterpret_cast<const int4*>(row + base);
        int4 a = r4[0], b = r4[1];
        atomicAdd(&cnt[a.x], 1); atomicAdd(&cnt[a.y], 1);
        atomicAdd(&cnt[a.z], 1); atomicAdd(&cnt[a.w], 1);
        atomicAdd(&cnt[b.x], 1); atomicAdd(&cnt[b.y], 1);
        atomicAdd(&cnt[b.z], 1); atomicAdd(&cnt[b.w], 1);
    } else {
        for (int e = base; e < nE; ++e) atomicAdd(&cnt[row[e]], 1);
    }
}

// ---------------- hierarchical exclusive scan, phase 1: block sums ----------
__global__ void __launch_bounds__(1024) k_scan_reduce(const int* __restrict__ cnt,
                                                      int* __restrict__ part, int n) {
    __shared__ int sd[1024];
    int i = blockIdx.x * SCAN_B + threadIdx.x;
    int v = (i < n) ? cnt[i] : 0;
    sd[threadIdx.x] = v;
    __syncthreads();
    for (int off = 512; off > 0; off >>= 1) {
        if (threadIdx.x < off) sd[threadIdx.x] += sd[threadIdx.x + off];
        __syncthreads();
    }
    if (threadIdx.x == 0) part[blockIdx.x] = sd[0];
}

// ---------------- phase 2: exclusive scan of partials (1 block) -------------
__global__ void __launch_bounds__(128) k_scan_part(int* __restrict__ part,
                                                   int* __restrict__ offs,
                                                   int nb, int n) {
    __shared__ int sd[128];
    int v = (threadIdx.x < nb) ? part[threadIdx.x] : 0;
    sd[threadIdx.x] = v;
    __syncthreads();
    for (int off = 1; off < 128; off <<= 1) {
        int t = (threadIdx.x >= off) ? sd[threadIdx.x - off] : 0;
        __syncthreads();
        sd[threadIdx.x] += t;
        __syncthreads();
    }
    if (threadIdx.x < nb) part[threadIdx.x] = sd[threadIdx.x] - v;  // exclusive
    if (threadIdx.x == 127) offs[n] = sd[127];                      // total
}

// ---- phase 3: per-block scan + add partial; dis; self-loop pre-insert ------
__global__ void __launch_bounds__(1024) k_scan_final(const int* __restrict__ cnt,
                                                     const int* __restrict__ part,
                                                     int* __restrict__ offs,
                                                     float* __restrict__ dis,
                                                     int* __restrict__ fill,
                                                     int* __restrict__ sc, int n) {
    __shared__ int sd[1024];
    int i = blockIdx.x * SCAN_B + threadIdx.x;
    int v = (i < n) ? cnt[i] : 0;
    sd[threadIdx.x] = v;
    __syncthreads();
    for (int off = 1; off < 1024; off <<= 1) {
        int t = (threadIdx.x >= off) ? sd[threadIdx.x - off] : 0;
        __syncthreads();
        sd[threadIdx.x] += t;
        __syncthreads();
    }
    if (i < n) {
        int o = part[blockIdx.x] + sd[threadIdx.x] - v;    // exclusive
        offs[i] = o;
        dis[i]  = rsqrtf((float)v);                        // v >= 1 (self loop)
        sc[o]   = i;                                       // self loop pre-inserted
        fill[i] = 1;
    }
}

// ---------------- CSR fill: 8 edges/thread, 8 atomics in flight -------------
__global__ void k_fill(const int* __restrict__ row, const int* __restrict__ col,
                       const int* __restrict__ offs, int* __restrict__ fill,
                       int* __restrict__ sc, int nE) {
    int t = blockIdx.x * 256 + threadIdx.x;
    int base = t * 8;
    if (base >= nE) return;
    if (base + 8 <= nE) {
        const int4* r4 = reinterpret_cast<const int4*>(row + base);
        const int4* c4 = reinterpret_cast<const int4*>(col + base);
        int4 ra = r4[0], rb = r4[1];
        int4 ca = c4[0], cb = c4[1];
        int p0 = atomicAdd(&fill[ra.x], 1);
        int p1 = atomicAdd(&fill[ra.y], 1);
        int p2 = atomicAdd(&fill[ra.z], 1);
        int p3 = atomicAdd(&fill[ra.w], 1);
        int p4 = atomicAdd(&fill[rb.x], 1);
        int p5 = atomicAdd(&fill[rb.y], 1);
        int p6 = atomicAdd(&fill[rb.z], 1);
        int p7 = atomicAdd(&fill[rb.w], 1);
        int o0 = offs[ra.x], o1 = offs[ra.y], o2 = offs[ra.z], o3 = offs[ra.w];
        int o4 = offs[rb.x], o5 = offs[rb.y], o6 = offs[rb.z], o7 = offs[rb.w];
        sc[o0 + p0] = ca.x; sc[o1 + p1] = ca.y;
        sc[o2 + p2] = ca.z; sc[o3 + p3] = ca.w;
        sc[o4 + p4] = cb.x; sc[o5 + p5] = cb.y;
        sc[o6 + p6] = cb.z; sc[o7 + p7] = cb.w;
    } else {
        for (int e = base; e < nE; ++e) {
            int r = row[e];
            int pos = offs[r] + atomicAdd(&fill[r], 1);
            sc[pos] = col[e];
        }
    }
}

// ---------------- support = dis[node] * (x @ W), stored fp16 ----------------
// Block: 256 threads = 128 features x 2 node-groups; 16 nodes per block.
__global__ void __launch_bounds__(256) k_gemm(const float* __restrict__ x,
                                              const float* __restrict__ w,
                                              const float* __restrict__ dis,
                                              __half* __restrict__ support, int n) {
    __shared__ float w_s[FDIM * FDIM];   // 64 KB
    __shared__ float x_s[16 * FDIM];     // 8 KB

    const float4* wg = reinterpret_cast<const float4*>(w);
    float4* ws4 = reinterpret_cast<float4*>(w_s);
    #pragma unroll
    for (int it = 0; it < 16; ++it)
        ws4[threadIdx.x + it * 256] = wg[threadIdx.x + it * 256];

    int nb = blockIdx.x * 16;                       // n = 100000 = 6250 * 16
    const float4* xg = reinterpret_cast<const float4*>(x + (size_t)nb * FDIM);
    float4* xs4w = reinterpret_cast<float4*>(x_s);
    #pragma unroll
    for (int it = 0; it < 2; ++it)
        xs4w[threadIdx.x + it * 256] = xg[threadIdx.x + it * 256];
    __syncthreads();

    int f  = threadIdx.x & 127;
    int ng = threadIdx.x >> 7;                      // 0..1 (8 nodes each)
    const float4* xs4 = reinterpret_cast<const float4*>(x_s);
    float acc[8] = {0, 0, 0, 0, 0, 0, 0, 0};
    for (int kg = 0; kg < 32; ++kg) {
        float w0 = w_s[(4 * kg + 0) * FDIM + f];
        float w1 = w_s[(4 * kg + 1) * FDIM + f];
        float w2 = w_s[(4 * kg + 2) * FDIM + f];
        float w3 = w_s[(4 * kg + 3) * FDIM + f];
        #pragma unroll
        for (int j = 0; j < 8; ++j) {
            float4 xv = xs4[(ng * 8 + j) * 32 + kg];   // wave-uniform -> broadcast
            acc[j] += xv.x * w0 + xv.y * w1 + xv.z * w2 + xv.w * w3;
        }
    }
    #pragma unroll
    for (int j = 0; j < 8; ++j) {
        int node = nb + ng * 8 + j;
        if (node < n)
            support[(size_t)node * FDIM + f] = __float2half(dis[node] * acc[j]);
    }
}

// ---------------- aggregation: one wave per node, half2 gathers -------------
__global__ void __launch_bounds__(64) k_agg(const __half2* __restrict__ sup2,
                                            const int* __restrict__ offs,
                                            const int* __restrict__ sc,
                                            const float* __restrict__ dis,
                                            const float* __restrict__ bias,
                                            float* __restrict__ out, int n) {
    int i  = blockIdx.x;
    int f2 = threadIdx.x;                           // 0..63 -> features 2f2,2f2+1
    int beg = offs[i], end = offs[i + 1];
    float ax = 0.f, ay = 0.f;
    int j = beg;
    for (; j + 4 <= end; j += 4) {
        int c0 = sc[j], c1 = sc[j + 1], c2 = sc[j + 2], c3 = sc[j + 3];
        float2 v0 = __half22float2(sup2[(size_t)c0 * 64 + f2]);
        float2 v1 = __half22float2(sup2[(size_t)c1 * 64 + f2]);
        float2 v2 = __half22float2(sup2[(size_t)c2 * 64 + f2]);
        float2 v3 = __half22float2(sup2[(size_t)c3 * 64 + f2]);
        ax += (v0.x + v1.x) + (v2.x + v3.x);
        ay += (v0.y + v1.y) + (v2.y + v3.y);
    }
    for (; j < end; ++j) {
        float2 v = __half22float2(sup2[(size_t)sc[j] * 64 + f2]);
        ax += v.x; ay += v.y;
    }
    float di = dis[i];
    const float2* b2 = reinterpret_cast<const float2*>(bias);
    float2 bb = b2[f2];
    float2 o;
    o.x = di * ax + bb.x;
    o.y = di * ay + bb.y;
    reinterpret_cast<float2*>(out)[(size_t)i * 64 + f2] = o;
}

extern "C" void kernel_launch(void* const* d_in, const int* in_sizes, int n_in,
                              void* d_out, int out_size, void* d_ws, size_t ws_size,
                              hipStream_t stream) {
    const float* x    = (const float*)d_in[0];
    const int*   ei   = (const int*)d_in[1];    // int32 on device (harness converts)
    const float* w    = (const float*)d_in[2];
    const float* bias = (const float*)d_in[3];
    float*       out  = (float*)d_out;

    int n  = in_sizes[0] / FDIM;   // 100000 nodes
    int nE = in_sizes[1] / 2;      // 3200000 edges
    const int* row = ei;
    const int* col = ei + nE;
    int nbscan = (n + SCAN_B - 1) / SCAN_B;     // 98 <= 128
    int nt8 = (nE + 7) / 8;                     // threads for 8-edge kernels

    // workspace carve-out (ws is re-poisoned every launch; we overwrite all)
    char* ws = (char*)d_ws;
    size_t off = 0;
    auto alloc = [&](size_t bytes) -> void* {
        void* p = ws + off;
        off += (bytes + 255) & ~(size_t)255;
        return p;
    };
    __half* support = (__half*)alloc((size_t)n * FDIM * sizeof(__half)); // 25.6 MB
    int*    cnt     = (int*)alloc((size_t)n * sizeof(int));
    int*    fill    = (int*)alloc((size_t)n * sizeof(int));
    int*    offs    = (int*)alloc((size_t)(n + 1) * sizeof(int));
    int*    part    = (int*)alloc((size_t)128 * sizeof(int));
    float*  dis     = (float*)alloc((size_t)n * sizeof(float));
    int*    sc      = (int*)alloc((size_t)(nE + n) * sizeof(int));     // 13.2 MB

    k_init       <<<(n + 255) / 256, 256, 0, stream>>>(cnt, n);
    k_count      <<<(nt8 + 255) / 256, 256, 0, stream>>>(row, cnt, nE);
    k_scan_reduce<<<nbscan, 1024, 0, stream>>>(cnt, part, n);
    k_scan_part  <<<1, 128, 0, stream>>>(part, offs, nbscan, n);
    k_scan_final <<<nbscan, 1024, 0, stream>>>(cnt, part, offs, dis, fill, sc, n);
    k_fill       <<<(nt8 + 255) / 256, 256, 0, stream>>>(row, col, offs, fill, sc, nE);
    k_gemm       <<<(n + 15) / 16, 256, 0, stream>>>(x, w, dis, support, n);
    k_agg        <<<n, 64, 0, stream>>>((const __half2*)support, offs, sc, dis, bias, out, n);
}

// Round 6
// 720.202 us; speedup vs baseline: 1.0051x; 1.0051x over previous
//
#include <hip/hip_runtime.h>
#include <hip/hip_fp16.h>

#define FDIM 128
#define SCAN_B 1024   // elements per scan block

// ---------------- init: self-loop degree ------------------------------------
__global__ void k_init(int* __restrict__ cnt, int n) {
    int i = blockIdx.x * 256 + threadIdx.x;
    if (i < n) cnt[i] = 1;
}

// ---------------- degree count: grid-stride, fire-and-forget atomics --------
__global__ void k_count(const int* __restrict__ row, int* __restrict__ cnt, int nE) {
    int stride = gridDim.x * blockDim.x;
    for (int e = blockIdx.x * blockDim.x + threadIdx.x; e < nE; e += stride)
        atomicAdd(&cnt[row[e]], 1);
}

// ---------------- hierarchical exclusive scan, phase 1: block sums ----------
__global__ void __launch_bounds__(1024) k_scan_reduce(const int* __restrict__ cnt,
                                                      int* __restrict__ part, int n) {
    __shared__ int sd[1024];
    int i = blockIdx.x * SCAN_B + threadIdx.x;
    int v = (i < n) ? cnt[i] : 0;
    sd[threadIdx.x] = v;
    __syncthreads();
    for (int off = 512; off > 0; off >>= 1) {
        if (threadIdx.x < off) sd[threadIdx.x] += sd[threadIdx.x + off];
        __syncthreads();
    }
    if (threadIdx.x == 0) part[blockIdx.x] = sd[0];
}

// ---------------- phase 2: exclusive scan of partials (1 block) -------------
__global__ void __launch_bounds__(128) k_scan_part(int* __restrict__ part,
                                                   int* __restrict__ offs,
                                                   int nb, int n) {
    __shared__ int sd[128];
    int v = (threadIdx.x < nb) ? part[threadIdx.x] : 0;
    sd[threadIdx.x] = v;
    __syncthreads();
    for (int off = 1; off < 128; off <<= 1) {
        int t = (threadIdx.x >= off) ? sd[threadIdx.x - off] : 0;
        __syncthreads();
        sd[threadIdx.x] += t;
        __syncthreads();
    }
    if (threadIdx.x < nb) part[threadIdx.x] = sd[threadIdx.x] - v;  // exclusive
    if (threadIdx.x == 127) offs[n] = sd[127];                      // total
}

// ---- phase 3: scan + add partial; dis; self-loop pre-insert; cursor --------
__global__ void __launch_bounds__(1024) k_scan_final(const int* __restrict__ cnt,
                                                     const int* __restrict__ part,
                                                     int* __restrict__ offs,
                                                     float* __restrict__ dis,
                                                     int* __restrict__ fill,
                                                     int* __restrict__ sc, int n) {
    __shared__ int sd[1024];
    int i = blockIdx.x * SCAN_B + threadIdx.x;
    int v = (i < n) ? cnt[i] : 0;
    sd[threadIdx.x] = v;
    __syncthreads();
    for (int off = 1; off < 1024; off <<= 1) {
        int t = (threadIdx.x >= off) ? sd[threadIdx.x - off] : 0;
        __syncthreads();
        sd[threadIdx.x] += t;
        __syncthreads();
    }
    if (i < n) {
        int o = part[blockIdx.x] + sd[threadIdx.x] - v;    // exclusive
        offs[i] = o;
        dis[i]  = rsqrtf((float)v);                        // v >= 1 (self loop)
        sc[o]   = i;                                       // self loop pre-inserted
        fill[i] = o + 1;                                   // absolute cursor
    }
}

// ---------------- CSR fill: cursor atomic, short chain ----------------------
// fill[r] holds the absolute next position: pos = atomicAdd(&fill[r], 1).
__global__ void k_fill(const int* __restrict__ row, const int* __restrict__ col,
                       int* __restrict__ fill, int* __restrict__ sc, int nE) {
    int stride = gridDim.x * blockDim.x;
    for (int e = blockIdx.x * blockDim.x + threadIdx.x; e < nE; e += stride) {
        int pos = atomicAdd(&fill[row[e]], 1);
        sc[pos] = col[e];
    }
}

// ---------------- support = dis[node] * (x @ W), stored fp16 ----------------
// Block: 256 threads = 128 features x 2 node-groups; 16 nodes per block.
__global__ void __launch_bounds__(256) k_gemm(const float* __restrict__ x,
                                              const float* __restrict__ w,
                                              const float* __restrict__ dis,
                                              __half* __restrict__ support, int n) {
    __shared__ float w_s[FDIM * FDIM];   // 64 KB
    __shared__ float x_s[16 * FDIM];     // 8 KB

    const float4* wg = reinterpret_cast<const float4*>(w);
    float4* ws4 = reinterpret_cast<float4*>(w_s);
    #pragma unroll
    for (int it = 0; it < 16; ++it)
        ws4[threadIdx.x + it * 256] = wg[threadIdx.x + it * 256];

    int nb = blockIdx.x * 16;                       // n = 100000 = 6250 * 16
    const float4* xg = reinterpret_cast<const float4*>(x + (size_t)nb * FDIM);
    float4* xs4w = reinterpret_cast<float4*>(x_s);
    #pragma unroll
    for (int it = 0; it < 2; ++it)
        xs4w[threadIdx.x + it * 256] = xg[threadIdx.x + it * 256];
    __syncthreads();

    int f  = threadIdx.x & 127;
    int ng = threadIdx.x >> 7;                      // 0..1 (8 nodes each)
    const float4* xs4 = reinterpret_cast<const float4*>(x_s);
    float acc[8] = {0, 0, 0, 0, 0, 0, 0, 0};
    for (int kg = 0; kg < 32; ++kg) {
        float w0 = w_s[(4 * kg + 0) * FDIM + f];
        float w1 = w_s[(4 * kg + 1) * FDIM + f];
        float w2 = w_s[(4 * kg + 2) * FDIM + f];
        float w3 = w_s[(4 * kg + 3) * FDIM + f];
        #pragma unroll
        for (int j = 0; j < 8; ++j) {
            float4 xv = xs4[(ng * 8 + j) * 32 + kg];   // wave-uniform -> broadcast
            acc[j] += xv.x * w0 + xv.y * w1 + xv.z * w2 + xv.w * w3;
        }
    }
    #pragma unroll
    for (int j = 0; j < 8; ++j) {
        int node = nb + ng * 8 + j;
        if (node < n)
            support[(size_t)node * FDIM + f] = __float2half(dis[node] * acc[j]);
    }
}

// ---------------- aggregation: one wave per node, half2 gathers -------------
__global__ void __launch_bounds__(64) k_agg(const __half2* __restrict__ sup2,
                                            const int* __restrict__ offs,
                                            const int* __restrict__ sc,
                                            const float* __restrict__ dis,
                                            const float* __restrict__ bias,
                                            float* __restrict__ out, int n) {
    int i  = blockIdx.x;
    int f2 = threadIdx.x;                           // 0..63 -> features 2f2,2f2+1
    int beg = offs[i], end = offs[i + 1];
    float ax = 0.f, ay = 0.f;
    int j = beg;
    for (; j + 4 <= end; j += 4) {
        int c0 = sc[j], c1 = sc[j + 1], c2 = sc[j + 2], c3 = sc[j + 3];
        float2 v0 = __half22float2(sup2[(size_t)c0 * 64 + f2]);
        float2 v1 = __half22float2(sup2[(size_t)c1 * 64 + f2]);
        float2 v2 = __half22float2(sup2[(size_t)c2 * 64 + f2]);
        float2 v3 = __half22float2(sup2[(size_t)c3 * 64 + f2]);
        ax += (v0.x + v1.x) + (v2.x + v3.x);
        ay += (v0.y + v1.y) + (v2.y + v3.y);
    }
    for (; j < end; ++j) {
        float2 v = __half22float2(sup2[(size_t)sc[j] * 64 + f2]);
        ax += v.x; ay += v.y;
    }
    float di = dis[i];
    const float2* b2 = reinterpret_cast<const float2*>(bias);
    float2 bb = b2[f2];
    float2 o;
    o.x = di * ax + bb.x;
    o.y = di * ay + bb.y;
    reinterpret_cast<float2*>(out)[(size_t)i * 64 + f2] = o;
}

extern "C" void kernel_launch(void* const* d_in, const int* in_sizes, int n_in,
                              void* d_out, int out_size, void* d_ws, size_t ws_size,
                              hipStream_t stream) {
    const float* x    = (const float*)d_in[0];
    const int*   ei   = (const int*)d_in[1];    // int32 on device (harness converts)
    const float* w    = (const float*)d_in[2];
    const float* bias = (const float*)d_in[3];
    float*       out  = (float*)d_out;

    int n  = in_sizes[0] / FDIM;   // 100000 nodes
    int nE = in_sizes[1] / 2;      // 3200000 edges
    const int* row = ei;
    const int* col = ei + nE;
    int nbscan = (n + SCAN_B - 1) / SCAN_B;     // 98 <= 128

    // workspace carve-out (ws is re-poisoned every launch; we overwrite all)
    char* ws = (char*)d_ws;
    size_t off = 0;
    auto alloc = [&](size_t bytes) -> void* {
        void* p = ws + off;
        off += (bytes + 255) & ~(size_t)255;
        return p;
    };
    __half* support = (__half*)alloc((size_t)n * FDIM * sizeof(__half)); // 25.6 MB
    int*    cnt     = (int*)alloc((size_t)n * sizeof(int));
    int*    fill    = (int*)alloc((size_t)n * sizeof(int));
    int*    offs    = (int*)alloc((size_t)(n + 1) * sizeof(int));
    int*    part    = (int*)alloc((size_t)128 * sizeof(int));
    float*  dis     = (float*)alloc((size_t)n * sizeof(float));
    int*    sc      = (int*)alloc((size_t)(nE + n) * sizeof(int));     // 13.2 MB

    k_init       <<<(n + 255) / 256, 256, 0, stream>>>(cnt, n);
    k_count      <<<2048, 256, 0, stream>>>(row, cnt, nE);
    k_scan_reduce<<<nbscan, 1024, 0, stream>>>(cnt, part, n);
    k_scan_part  <<<1, 128, 0, stream>>>(part, offs, nbscan, n);
    k_scan_final <<<nbscan, 1024, 0, stream>>>(cnt, part, offs, dis, fill, sc, n);
    k_fill       <<<2048, 256, 0, stream>>>(row, col, fill, sc, nE);
    k_gemm       <<<(n + 15) / 16, 256, 0, stream>>>(x, w, dis, support, n);
    k_agg        <<<n, 64, 0, stream>>>((const __half2*)support, offs, sc, dis, bias, out, n);
}

// Round 7
// 544.392 us; speedup vs baseline: 1.3297x; 1.3229x over previous
//
#include <hip/hip_runtime.h>
#include <hip/hip_fp16.h>

#define FDIM 128
#define SCAN_B 1024   // elements per scan block
#define NBUCKET 8     // one per XCD
#define NCHUNK 256    // edge chunks

// ---------------- init: self-loop degree ------------------------------------
__global__ void k_init(int* __restrict__ cnt, int n) {
    int i = blockIdx.x * 256 + threadIdx.x;
    if (i < n) cnt[i] = 1;
}

// ------ degree count; atomic return value = rank of edge within its row -----
__global__ void k_count(const int* __restrict__ row, int* __restrict__ cnt,
                        int* __restrict__ rank, int nE) {
    int stride = gridDim.x * blockDim.x;
    for (int e = blockIdx.x * blockDim.x + threadIdx.x; e < nE; e += stride)
        rank[e] = atomicAdd(&cnt[row[e]], 1);   // ranks start at 1 (slot 0 = self loop)
}

// ---------------- hierarchical exclusive scan, phase 1: block sums ----------
__global__ void __launch_bounds__(1024) k_scan_reduce(const int* __restrict__ cnt,
                                                      int* __restrict__ part, int n) {
    __shared__ int sd[1024];
    int i = blockIdx.x * SCAN_B + threadIdx.x;
    int v = (i < n) ? cnt[i] : 0;
    sd[threadIdx.x] = v;
    __syncthreads();
    for (int off = 512; off > 0; off >>= 1) {
        if (threadIdx.x < off) sd[threadIdx.x] += sd[threadIdx.x + off];
        __syncthreads();
    }
    if (threadIdx.x == 0) part[blockIdx.x] = sd[0];
}

// ---------------- phase 2: exclusive scan of partials (1 block) -------------
__global__ void __launch_bounds__(128) k_scan_part(int* __restrict__ part,
                                                   int* __restrict__ offs,
                                                   int nb, int n) {
    __shared__ int sd[128];
    int v = (threadIdx.x < nb) ? part[threadIdx.x] : 0;
    sd[threadIdx.x] = v;
    __syncthreads();
    for (int off = 1; off < 128; off <<= 1) {
        int t = (threadIdx.x >= off) ? sd[threadIdx.x - off] : 0;
        __syncthreads();
        sd[threadIdx.x] += t;
        __syncthreads();
    }
    if (threadIdx.x < nb) part[threadIdx.x] = sd[threadIdx.x] - v;  // exclusive
    if (threadIdx.x == 127) offs[n] = sd[127];                      // total
}

// ---- phase 3: scan + add partial; dis; self-loop pre-insert ----------------
__global__ void __launch_bounds__(1024) k_scan_final(const int* __restrict__ cnt,
                                                     const int* __restrict__ part,
                                                     int* __restrict__ offs,
                                                     float* __restrict__ dis,
                                                     int* __restrict__ sc, int n) {
    __shared__ int sd[1024];
    int i = blockIdx.x * SCAN_B + threadIdx.x;
    int v = (i < n) ? cnt[i] : 0;
    sd[threadIdx.x] = v;
    __syncthreads();
    for (int off = 1; off < 1024; off <<= 1) {
        int t = (threadIdx.x >= off) ? sd[threadIdx.x - off] : 0;
        __syncthreads();
        sd[threadIdx.x] += t;
        __syncthreads();
    }
    if (i < n) {
        int o = part[blockIdx.x] + sd[threadIdx.x] - v;    // exclusive
        offs[i] = o;
        dis[i]  = rsqrtf((float)v);                        // v >= 1 (self loop)
        sc[o]   = i;                                       // self loop at slot 0
    }
}

// ---------------- CSR fill: no atomics, XCD-bucketed scatter ----------------
// Block b: bucket = b & 7 (round-robin block->XCD), chunk = b >> 3.
// Bucket k's sc region (~1.65 MB) stays resident in one XCD's L2 ->
// full-line evictions instead of 64B-per-4B churn.
__global__ void __launch_bounds__(256) k_fill(const int* __restrict__ row,
                                              const int* __restrict__ col,
                                              const int* __restrict__ rank,
                                              const int* __restrict__ offs,
                                              int* __restrict__ sc,
                                              int nE, int bspan) {
    int bucket = blockIdx.x & (NBUCKET - 1);
    int chunk  = blockIdx.x >> 3;
    int per = (nE + NCHUNK - 1) / NCHUNK;
    int beg = chunk * per;
    int end = beg + per; if (end > nE) end = nE;
    int lo = bucket * bspan;
    int hi = lo + bspan;
    for (int e = beg + threadIdx.x; e < end; e += 256) {
        int r = row[e];
        if (r >= lo && r < hi)
            sc[offs[r] + rank[e]] = col[e];
    }
}

// ---------------- support = dis[node] * (x @ W), stored fp16 ----------------
// Block: 256 threads = 128 features x 2 node-groups; 16 nodes per block.
__global__ void __launch_bounds__(256) k_gemm(const float* __restrict__ x,
                                              const float* __restrict__ w,
                                              const float* __restrict__ dis,
                                              __half* __restrict__ support, int n) {
    __shared__ float w_s[FDIM * FDIM];   // 64 KB
    __shared__ float x_s[16 * FDIM];     // 8 KB

    const float4* wg = reinterpret_cast<const float4*>(w);
    float4* ws4 = reinterpret_cast<float4*>(w_s);
    #pragma unroll
    for (int it = 0; it < 16; ++it)
        ws4[threadIdx.x + it * 256] = wg[threadIdx.x + it * 256];

    int nb = blockIdx.x * 16;                       // n = 100000 = 6250 * 16
    const float4* xg = reinterpret_cast<const float4*>(x + (size_t)nb * FDIM);
    float4* xs4w = reinterpret_cast<float4*>(x_s);
    #pragma unroll
    for (int it = 0; it < 2; ++it)
        xs4w[threadIdx.x + it * 256] = xg[threadIdx.x + it * 256];
    __syncthreads();

    int f  = threadIdx.x & 127;
    int ng = threadIdx.x >> 7;                      // 0..1 (8 nodes each)
    const float4* xs4 = reinterpret_cast<const float4*>(x_s);
    float acc[8] = {0, 0, 0, 0, 0, 0, 0, 0};
    for (int kg = 0; kg < 32; ++kg) {
        float w0 = w_s[(4 * kg + 0) * FDIM + f];
        float w1 = w_s[(4 * kg + 1) * FDIM + f];
        float w2 = w_s[(4 * kg + 2) * FDIM + f];
        float w3 = w_s[(4 * kg + 3) * FDIM + f];
        #pragma unroll
        for (int j = 0; j < 8; ++j) {
            float4 xv = xs4[(ng * 8 + j) * 32 + kg];   // wave-uniform -> broadcast
            acc[j] += xv.x * w0 + xv.y * w1 + xv.z * w2 + xv.w * w3;
        }
    }
    #pragma unroll
    for (int j = 0; j < 8; ++j) {
        int node = nb + ng * 8 + j;
        if (node < n)
            support[(size_t)node * FDIM + f] = __float2half(dis[node] * acc[j]);
    }
}

// ---------------- aggregation: one wave per node, half2 gathers -------------
__global__ void __launch_bounds__(64) k_agg(const __half2* __restrict__ sup2,
                                            const int* __restrict__ offs,
                                            const int* __restrict__ sc,
                                            const float* __restrict__ dis,
                                            const float* __restrict__ bias,
                                            float* __restrict__ out, int n) {
    int i  = blockIdx.x;
    int f2 = threadIdx.x;                           // 0..63 -> features 2f2,2f2+1
    int beg = offs[i], end = offs[i + 1];
    float ax = 0.f, ay = 0.f;
    int j = beg;
    for (; j + 4 <= end; j += 4) {
        int c0 = sc[j], c1 = sc[j + 1], c2 = sc[j + 2], c3 = sc[j + 3];
        float2 v0 = __half22float2(sup2[(size_t)c0 * 64 + f2]);
        float2 v1 = __half22float2(sup2[(size_t)c1 * 64 + f2]);
        float2 v2 = __half22float2(sup2[(size_t)c2 * 64 + f2]);
        float2 v3 = __half22float2(sup2[(size_t)c3 * 64 + f2]);
        ax += (v0.x + v1.x) + (v2.x + v3.x);
        ay += (v0.y + v1.y) + (v2.y + v3.y);
    }
    for (; j < end; ++j) {
        float2 v = __half22float2(sup2[(size_t)sc[j] * 64 + f2]);
        ax += v.x; ay += v.y;
    }
    float di = dis[i];
    const float2* b2 = reinterpret_cast<const float2*>(bias);
    float2 bb = b2[f2];
    float2 o;
    o.x = di * ax + bb.x;
    o.y = di * ay + bb.y;
    reinterpret_cast<float2*>(out)[(size_t)i * 64 + f2] = o;
}

extern "C" void kernel_launch(void* const* d_in, const int* in_sizes, int n_in,
                              void* d_out, int out_size, void* d_ws, size_t ws_size,
                              hipStream_t stream) {
    const float* x    = (const float*)d_in[0];
    const int*   ei   = (const int*)d_in[1];    // int32 on device (harness converts)
    const float* w    = (const float*)d_in[2];
    const float* bias = (const float*)d_in[3];
    float*       out  = (float*)d_out;

    int n  = in_sizes[0] / FDIM;   // 100000 nodes
    int nE = in_sizes[1] / 2;      // 3200000 edges
    const int* row = ei;
    const int* col = ei + nE;
    int nbscan = (n + SCAN_B - 1) / SCAN_B;          // 98 <= 128
    int bspan  = (n + NBUCKET - 1) / NBUCKET;        // 12500 rows per bucket

    // workspace carve-out (ws is re-poisoned every launch; we overwrite all)
    char* ws = (char*)d_ws;
    size_t off = 0;
    auto alloc = [&](size_t bytes) -> void* {
        void* p = ws + off;
        off += (bytes + 255) & ~(size_t)255;
        return p;
    };
    __half* support = (__half*)alloc((size_t)n * FDIM * sizeof(__half)); // 25.6 MB
    int*    cnt     = (int*)alloc((size_t)n * sizeof(int));
    int*    offs    = (int*)alloc((size_t)(n + 1) * sizeof(int));
    int*    part    = (int*)alloc((size_t)128 * sizeof(int));
    float*  dis     = (float*)alloc((size_t)n * sizeof(float));
    int*    sc      = (int*)alloc((size_t)(nE + n) * sizeof(int));     // 13.2 MB
    int*    rank    = (int*)alloc((size_t)nE * sizeof(int));           // 12.8 MB

    k_init       <<<(n + 255) / 256, 256, 0, stream>>>(cnt, n);
    k_count      <<<2048, 256, 0, stream>>>(row, cnt, rank, nE);
    k_scan_reduce<<<nbscan, 1024, 0, stream>>>(cnt, part, n);
    k_scan_part  <<<1, 128, 0, stream>>>(part, offs, nbscan, n);
    k_scan_final <<<nbscan, 1024, 0, stream>>>(cnt, part, offs, dis, sc, n);
    k_fill       <<<NCHUNK * NBUCKET, 256, 0, stream>>>(row, col, rank, offs, sc, nE, bspan);
    k_gemm       <<<(n + 15) / 16, 256, 0, stream>>>(x, w, dis, support, n);
    k_agg        <<<n, 64, 0, stream>>>((const __half2*)support, offs, sc, dis, bias, out, n);
}

// Round 8
// 535.309 us; speedup vs baseline: 1.3523x; 1.0170x over previous
//
#include <hip/hip_runtime.h>
#include <hip/hip_fp16.h>

#define FDIM 128
#define SCAN_B 1024   // elements per scan block
#define NBUCKET 8     // node-range buckets for fill
#define NCHUNK 256    // edge chunks
#define NXCD 8

// Physical XCD id of the CU this block runs on (HW-verified on gfx950).
__device__ __forceinline__ int xcc_id() {
    int x;
    asm volatile("s_getreg_b32 %0, hwreg(HW_REG_XCC_ID)" : "=s"(x));
    return x & (NXCD - 1);
}

// ---------------- zero the per-XCD count copies -----------------------------
__global__ void k_zero(int* __restrict__ cnt8, int total) {
    int stride = gridDim.x * 256;
    for (int i = blockIdx.x * 256 + threadIdx.x; i < total; i += stride)
        cnt8[i] = 0;
}

// ------ degree count into XCD-private copy; L2-local atomics ----------------
// Copy x is only ever touched by blocks physically on XCD x, so an
// XCD(L2)-scope atomic is sufficient — no device-scope write-through.
__global__ void k_count(const int* __restrict__ row, int* __restrict__ cnt8,
                        int* __restrict__ rank, int nE, int n) {
    int x = xcc_id();
    int* cnt = cnt8 + (size_t)x * n;
    int stride = gridDim.x * blockDim.x;
    for (int e = blockIdx.x * blockDim.x + threadIdx.x; e < nE; e += stride) {
        int lr = __hip_atomic_fetch_add(&cnt[row[e]], 1,
                                        __ATOMIC_RELAXED, __HIP_MEMORY_SCOPE_WORKGROUP);
        rank[e] = (x << 24) | lr;
    }
}

// ---------------- hierarchical exclusive scan, phase 1: block sums ----------
__global__ void __launch_bounds__(1024) k_scan_reduce(const int* __restrict__ cnt8,
                                                      int* __restrict__ part, int n) {
    __shared__ int sd[1024];
    int i = blockIdx.x * SCAN_B + threadIdx.x;
    int v = 0;
    if (i < n) {
        v = 1;                                   // self loop
        #pragma unroll
        for (int x = 0; x < NXCD; ++x) v += cnt8[(size_t)x * n + i];
    }
    sd[threadIdx.x] = v;
    __syncthreads();
    for (int off = 512; off > 0; off >>= 1) {
        if (threadIdx.x < off) sd[threadIdx.x] += sd[threadIdx.x + off];
        __syncthreads();
    }
    if (threadIdx.x == 0) part[blockIdx.x] = sd[0];
}

// ---------------- phase 2: exclusive scan of partials (1 block) -------------
__global__ void __launch_bounds__(128) k_scan_part(int* __restrict__ part,
                                                   int* __restrict__ offs,
                                                   int nb, int n) {
    __shared__ int sd[128];
    int v = (threadIdx.x < nb) ? part[threadIdx.x] : 0;
    sd[threadIdx.x] = v;
    __syncthreads();
    for (int off = 1; off < 128; off <<= 1) {
        int t = (threadIdx.x >= off) ? sd[threadIdx.x - off] : 0;
        __syncthreads();
        sd[threadIdx.x] += t;
        __syncthreads();
    }
    if (threadIdx.x < nb) part[threadIdx.x] = sd[threadIdx.x] - v;  // exclusive
    if (threadIdx.x == 127) offs[n] = sd[127];                      // total
}

// ---- phase 3: scan + partial; dis; self-loop; per-XCD base offsets ---------
__global__ void __launch_bounds__(1024) k_scan_final(const int* __restrict__ cnt8,
                                                     const int* __restrict__ part,
                                                     int* __restrict__ offs,
                                                     float* __restrict__ dis,
                                                     int* __restrict__ sc,
                                                     int* __restrict__ base8, int n) {
    __shared__ int sd[1024];
    int i = blockIdx.x * SCAN_B + threadIdx.x;
    int c[NXCD];
    int v = 0;
    if (i < n) {
        v = 1;
        #pragma unroll
        for (int x = 0; x < NXCD; ++x) { c[x] = cnt8[(size_t)x * n + i]; v += c[x]; }
    }
    sd[threadIdx.x] = v;
    __syncthreads();
    for (int off = 1; off < 1024; off <<= 1) {
        int t = (threadIdx.x >= off) ? sd[threadIdx.x - off] : 0;
        __syncthreads();
        sd[threadIdx.x] += t;
        __syncthreads();
    }
    if (i < n) {
        int o = part[blockIdx.x] + sd[threadIdx.x] - v;    // exclusive
        offs[i] = o;
        dis[i]  = rsqrtf((float)v);                        // v >= 1 (self loop)
        sc[o]   = i;                                       // self loop at slot 0
        int b = 1;                                         // slot 0 = self loop
        int base[NXCD];
        #pragma unroll
        for (int x = 0; x < NXCD; ++x) { base[x] = b; b += c[x]; }
        int4* bp = reinterpret_cast<int4*>(base8 + (size_t)i * 8);
        bp[0] = make_int4(base[0], base[1], base[2], base[3]);
        bp[1] = make_int4(base[4], base[5], base[6], base[7]);
    }
}

// ---------------- CSR fill: no atomics, node-bucketed scatter ---------------
// Block b: bucket = b & 7, chunk = b >> 3. Bucket k's sc region (~1.65 MB)
// stays L2-resident -> full-line evictions instead of 32B write-through.
__global__ void __launch_bounds__(256) k_fill(const int* __restrict__ row,
                                              const int* __restrict__ col,
                                              const int* __restrict__ rank,
                                              const int* __restrict__ offs,
                                              const int* __restrict__ base8,
                                              int* __restrict__ sc,
                                              int nE, int bspan) {
    int bucket = blockIdx.x & (NBUCKET - 1);
    int chunk  = blockIdx.x >> 3;
    int per = (nE + NCHUNK - 1) / NCHUNK;
    int beg = chunk * per;
    int end = beg + per; if (end > nE) end = nE;
    int lo = bucket * bspan;
    int hi = lo + bspan;
    for (int e = beg + threadIdx.x; e < end; e += 256) {
        int r = row[e];
        if (r >= lo && r < hi) {
            int rk = rank[e];
            int x  = rk >> 24;
            int lr = rk & 0xFFFFFF;
            sc[offs[r] + base8[(size_t)r * 8 + x] + lr] = col[e];
        }
    }
}

// ---------------- support = dis[node] * (x @ W), stored fp16 ----------------
// Block: 256 threads = 128 features x 2 node-groups; 16 nodes per block.
__global__ void __launch_bounds__(256) k_gemm(const float* __restrict__ x,
                                              const float* __restrict__ w,
                                              const float* __restrict__ dis,
                                              __half* __restrict__ support, int n) {
    __shared__ float w_s[FDIM * FDIM];   // 64 KB
    __shared__ float x_s[16 * FDIM];     // 8 KB

    const float4* wg = reinterpret_cast<const float4*>(w);
    float4* ws4 = reinterpret_cast<float4*>(w_s);
    #pragma unroll
    for (int it = 0; it < 16; ++it)
        ws4[threadIdx.x + it * 256] = wg[threadIdx.x + it * 256];

    int nb = blockIdx.x * 16;                       // n = 100000 = 6250 * 16
    const float4* xg = reinterpret_cast<const float4*>(x + (size_t)nb * FDIM);
    float4* xs4w = reinterpret_cast<float4*>(x_s);
    #pragma unroll
    for (int it = 0; it < 2; ++it)
        xs4w[threadIdx.x + it * 256] = xg[threadIdx.x + it * 256];
    __syncthreads();

    int f  = threadIdx.x & 127;
    int ng = threadIdx.x >> 7;                      // 0..1 (8 nodes each)
    const float4* xs4 = reinterpret_cast<const float4*>(x_s);
    float acc[8] = {0, 0, 0, 0, 0, 0, 0, 0};
    for (int kg = 0; kg < 32; ++kg) {
        float w0 = w_s[(4 * kg + 0) * FDIM + f];
        float w1 = w_s[(4 * kg + 1) * FDIM + f];
        float w2 = w_s[(4 * kg + 2) * FDIM + f];
        float w3 = w_s[(4 * kg + 3) * FDIM + f];
        #pragma unroll
        for (int j = 0; j < 8; ++j) {
            float4 xv = xs4[(ng * 8 + j) * 32 + kg];   // wave-uniform -> broadcast
            acc[j] += xv.x * w0 + xv.y * w1 + xv.z * w2 + xv.w * w3;
        }
    }
    #pragma unroll
    for (int j = 0; j < 8; ++j) {
        int node = nb + ng * 8 + j;
        if (node < n)
            support[(size_t)node * FDIM + f] = __float2half(dis[node] * acc[j]);
    }
}

// ---------------- aggregation: one wave per node, half2 gathers -------------
__global__ void __launch_bounds__(64) k_agg(const __half2* __restrict__ sup2,
                                            const int* __restrict__ offs,
                                            const int* __restrict__ sc,
                                            const float* __restrict__ dis,
                                            const float* __restrict__ bias,
                                            float* __restrict__ out, int n) {
    int i  = blockIdx.x;
    int f2 = threadIdx.x;                           // 0..63 -> features 2f2,2f2+1
    int beg = offs[i], end = offs[i + 1];
    float ax = 0.f, ay = 0.f;
    int j = beg;
    for (; j + 4 <= end; j += 4) {
        int c0 = sc[j], c1 = sc[j + 1], c2 = sc[j + 2], c3 = sc[j + 3];
        float2 v0 = __half22float2(sup2[(size_t)c0 * 64 + f2]);
        float2 v1 = __half22float2(sup2[(size_t)c1 * 64 + f2]);
        float2 v2 = __half22float2(sup2[(size_t)c2 * 64 + f2]);
        float2 v3 = __half22float2(sup2[(size_t)c3 * 64 + f2]);
        ax += (v0.x + v1.x) + (v2.x + v3.x);
        ay += (v0.y + v1.y) + (v2.y + v3.y);
    }
    for (; j < end; ++j) {
        float2 v = __half22float2(sup2[(size_t)sc[j] * 64 + f2]);
        ax += v.x; ay += v.y;
    }
    float di = dis[i];
    const float2* b2 = reinterpret_cast<const float2*>(bias);
    float2 bb = b2[f2];
    float2 o;
    o.x = di * ax + bb.x;
    o.y = di * ay + bb.y;
    reinterpret_cast<float2*>(out)[(size_t)i * 64 + f2] = o;
}

extern "C" void kernel_launch(void* const* d_in, const int* in_sizes, int n_in,
                              void* d_out, int out_size, void* d_ws, size_t ws_size,
                              hipStream_t stream) {
    const float* x    = (const float*)d_in[0];
    const int*   ei   = (const int*)d_in[1];    // int32 on device (harness converts)
    const float* w    = (const float*)d_in[2];
    const float* bias = (const float*)d_in[3];
    float*       out  = (float*)d_out;

    int n  = in_sizes[0] / FDIM;   // 100000 nodes
    int nE = in_sizes[1] / 2;      // 3200000 edges
    const int* row = ei;
    const int* col = ei + nE;
    int nbscan = (n + SCAN_B - 1) / SCAN_B;          // 98 <= 128
    int bspan  = (n + NBUCKET - 1) / NBUCKET;        // 12500 rows per bucket

    // workspace carve-out (ws is re-poisoned every launch; we overwrite all)
    char* ws = (char*)d_ws;
    size_t off = 0;
    auto alloc = [&](size_t bytes) -> void* {
        void* p = ws + off;
        off += (bytes + 255) & ~(size_t)255;
        return p;
    };
    __half* support = (__half*)alloc((size_t)n * FDIM * sizeof(__half)); // 25.6 MB
    int*    cnt8    = (int*)alloc((size_t)NXCD * n * sizeof(int));       //  3.2 MB
    int*    base8   = (int*)alloc((size_t)n * 8 * sizeof(int));          //  3.2 MB
    int*    offs    = (int*)alloc((size_t)(n + 1) * sizeof(int));
    int*    part    = (int*)alloc((size_t)128 * sizeof(int));
    float*  dis     = (float*)alloc((size_t)n * sizeof(float));
    int*    sc      = (int*)alloc((size_t)(nE + n) * sizeof(int));       // 13.2 MB
    int*    rank    = (int*)alloc((size_t)nE * sizeof(int));             // 12.8 MB

    k_zero       <<<512, 256, 0, stream>>>(cnt8, NXCD * n);
    k_count      <<<2048, 256, 0, stream>>>(row, cnt8, rank, nE, n);
    k_scan_reduce<<<nbscan, 1024, 0, stream>>>(cnt8, part, n);
    k_scan_part  <<<1, 128, 0, stream>>>(part, offs, nbscan, n);
    k_scan_final <<<nbscan, 1024, 0, stream>>>(cnt8, part, offs, dis, sc, base8, n);
    k_fill       <<<NCHUNK * NBUCKET, 256, 0, stream>>>(row, col, rank, offs, base8, sc, nE, bspan);
    k_gemm       <<<(n + 15) / 16, 256, 0, stream>>>(x, w, dis, support, n);
    k_agg        <<<n, 64, 0, stream>>>((const __half2*)support, offs, sc, dis, bias, out, n);
}